// Round 13
// baseline (489.710 us; speedup 1.0000x reference)
//
#include <hip/hip_runtime.h>
#include <cmath>

#define BB 128
#define TT 4096
#define NN 48

typedef short bf16x8 __attribute__((ext_vector_type(8)));
typedef short bf16x4 __attribute__((ext_vector_type(4)));
typedef float f32x4 __attribute__((ext_vector_type(4)));
typedef int   i32x4 __attribute__((ext_vector_type(4)));
typedef int   i32x2 __attribute__((ext_vector_type(2)));

__device__ __forceinline__ float wave_reduce_sum(float v) {
  #pragma unroll
  for (int m = 32; m >= 1; m >>= 1) v += __shfl_xor(v, m, 64);
  return v;
}
__device__ __forceinline__ int bperm(int byteidx, int src) {
  return __builtin_amdgcn_ds_bpermute(byteidx, src);
}
__device__ __forceinline__ float lane_bcast(float x, int lane) {
  return __uint_as_float((unsigned)__builtin_amdgcn_readlane(__float_as_int(x), lane));
}
__device__ __forceinline__ int cvt_pk_bf16(float lo, float hi) {
  int r;
  asm("v_cvt_pk_bf16_f32 %0, %1, %2" : "=v"(r) : "v"(lo), "v"(hi));
  return r;
}
__device__ __forceinline__ unsigned short f2bf(float f) {  // RNE f32->bf16
  unsigned u = __float_as_uint(f);
  unsigned r = (u + 0x7FFFu + ((u >> 16) & 1u)) >> 16;
  return (unsigned short)r;
}

// ---------------- Phase 1: per-(batch,chunk) transition-matrix product ----
// R6-verified math (absmax 0.0): Y <- diag(w_t) * E^T * Y, K-space relabel so
// C-words == next B-words verbatim; w via 12 f32 ds_bpermute per step.
// R13: occupancy doubling. NC=64 (CL=64) -> 8192 one-wave blocks = 8 waves/
// SIMD (full 32/CU residency); amdgpu_waves_per_eu(8) caps the register
// budget at 64 VGPR (measured natural usage: 60). Rationale: R6/R8/R12 all
// wall at ~120 us with MFMA 55% / VALU 60% / DS ~50% -- a latency-overlap
// deficit at 4 waves/SIMD, not a throughput wall. 2x resident chains fill
// the per-step dependency-chain bubbles.
template<int NC, int CL>
__global__ __launch_bounds__(64) __attribute__((amdgpu_waves_per_eu(8)))
void crf_chunk_kernel(const float* __restrict__ em,
                      const float* __restrict__ trans,
                      const int* __restrict__ tags,
                      unsigned short* __restrict__ G,
                      float* __restrict__ sc_part) {
  const int blk = blockIdx.x;
  const int b = blk / NC;
  const int c = blk % NC;
  const int l = threadIdx.x;
  const int g = l >> 4;
  const int rr = l & 15;
  const int jc = (l < NN) ? l : (NN - 1);
  const float FSCALE = 1.0f / 48.0f;

  // ---- static A = E^T/48. K-tile0 (16x16x32): label phi(g,e)=16*(e>>2)+4g+(e&3)
  //      K-tile1 (16x16x16): label psi(g,e)=32+4g+e
  bf16x8 Af0[3];
  bf16x4 Af1[3];
  #pragma unroll
  for (int mt = 0; mt < 3; ++mt) {
    const int i = 16 * mt + rr;
    bf16x8 a0;
    bf16x4 a1;
    #pragma unroll
    for (int e = 0; e < 8; ++e) {
      int k0 = 16 * (e >> 2) + 4 * g + (e & 3);
      a0[e] = (short)f2bf(__expf(trans[k0 * NN + i]) * FSCALE);
    }
    #pragma unroll
    for (int e = 0; e < 4; ++e) {
      int k1 = 32 + 4 * g + e;
      a1[e] = (short)f2bf(__expf(trans[k1 * NN + i]) * FSCALE);
    }
    Af0[mt] = a0; Af1[mt] = a1;
  }

  // ---- persistent state: Y = I in B-quad encoding.
  i32x4 B0s[3];
  i32x2 B1s[3];
  #pragma unroll
  for (int nt = 0; nt < 3; ++nt) {
    const int col = 16 * nt + rr;
    i32x4 b0;
    i32x2 b1;
    #pragma unroll
    for (int w = 0; w < 4; ++w) {
      int r0 = 16 * (w >> 1) + 4 * g + 2 * (w & 1);
      b0[w] = ((r0 == col) ? 0x3F80 : 0) | (((r0 + 1 == col) ? 0x3F80 : 0) << 16);
    }
    #pragma unroll
    for (int w = 0; w < 2; ++w) {
      int r0 = 32 + 4 * g + 2 * w;
      b1[w] = ((r0 == col) ? 0x3F80 : 0) | (((r0 + 1 == col) ? 0x3F80 : 0) << 16);
    }
    B0s[nt] = b0; B1s[nt] = b1;
  }

  const f32x4 zq = {0.f, 0.f, 0.f, 0.f};

  const int wbyte = g << 4;  // byte idx of lane 4g (R6-verified)

  const float* embr = em + (size_t)b * TT * NN + jc;
  const int t0 = c * CL + 1;

  // 8-deep emission prefetch (named registers)
  float pf0 = embr[(size_t)(t0 + 0) * NN];
  float pf1 = embr[(size_t)(t0 + 1) * NN];
  float pf2 = embr[(size_t)(t0 + 2) * NN];
  float pf3 = embr[(size_t)(t0 + 3) * NN];
  float pf4 = embr[(size_t)(t0 + 4) * NN];
  float pf5 = embr[(size_t)(t0 + 5) * NN];
  float pf6 = embr[(size_t)(t0 + 6) * NN];
  float pf7 = embr[(size_t)(t0 + 7) * NN];

  // core of one step, given w already in wi_
  #define BODY() do {                                                         \
    float wb_[12];                                                            \
    _Pragma("unroll") for (int mt = 0; mt < 3; ++mt)                          \
    _Pragma("unroll") for (int r = 0; r < 4; ++r)                             \
      wb_[mt * 4 + r] =                                                       \
          __uint_as_float((unsigned)bperm(wbyte + mt * 64 + r * 4, wi_));     \
    _Pragma("unroll") for (int nt = 0; nt < 3; ++nt) {                        \
      bf16x4 b1c_ = __builtin_bit_cast(bf16x4, B1s[nt]);                      \
      bf16x8 b0c_ = __builtin_bit_cast(bf16x8, B0s[nt]);                      \
      f32x4 a0_ = __builtin_amdgcn_mfma_f32_16x16x16bf16_1k(Af1[0], b1c_, zq, 0, 0, 0); \
      f32x4 a1_ = __builtin_amdgcn_mfma_f32_16x16x16bf16_1k(Af1[1], b1c_, zq, 0, 0, 0); \
      f32x4 a2_ = __builtin_amdgcn_mfma_f32_16x16x16bf16_1k(Af1[2], b1c_, zq, 0, 0, 0); \
      a0_ = __builtin_amdgcn_mfma_f32_16x16x32_bf16(Af0[0], b0c_, a0_, 0, 0, 0); \
      a1_ = __builtin_amdgcn_mfma_f32_16x16x32_bf16(Af0[1], b0c_, a1_, 0, 0, 0); \
      a2_ = __builtin_amdgcn_mfma_f32_16x16x32_bf16(Af0[2], b0c_, a2_, 0, 0, 0); \
      B0s[nt][0] = cvt_pk_bf16(a0_[0] * wb_[0],  a0_[1] * wb_[1]);            \
      B0s[nt][1] = cvt_pk_bf16(a0_[2] * wb_[2],  a0_[3] * wb_[3]);            \
      B0s[nt][2] = cvt_pk_bf16(a1_[0] * wb_[4],  a1_[1] * wb_[5]);            \
      B0s[nt][3] = cvt_pk_bf16(a1_[2] * wb_[6],  a1_[3] * wb_[7]);            \
      B1s[nt][0] = cvt_pk_bf16(a2_[0] * wb_[8],  a2_[1] * wb_[9]);            \
      B1s[nt][1] = cvt_pk_bf16(a2_[2] * wb_[10], a2_[3] * wb_[11]);           \
    }                                                                         \
  } while (0)

  // fast step: prefetch via pointer + folded immediate offset
  #define STEPF(PF, NPTR) do {                                                \
    float w_ = __expf(PF);                                                    \
    PF = *(NPTR);                                                             \
    int wi_ = __float_as_int(w_);                                             \
    BODY();                                                                   \
  } while (0)

  // clamped step: index form, only for the last chunk's tail
  #define STEPC(PF, NEXT_T) do {                                              \
    float w_ = __expf(PF);                                                    \
    int nxt_ = (NEXT_T) > (TT - 1) ? (TT - 1) : (NEXT_T);                     \
    PF = embr[(size_t)nxt_ * NN];                                             \
    int wi_ = __float_as_int(w_);                                             \
    BODY();                                                                   \
  } while (0)

  if (c != NC - 1) {
    // CL steps; prefetch may read up to 8 rows into the next chunk (in-bounds).
    const float* pref = embr + (size_t)(t0 + 8) * NN;
    #pragma unroll 1
    for (int it = 0; it < CL / 8; ++it) {
      STEPF(pf0, pref + 0 * NN);
      STEPF(pf1, pref + 1 * NN);
      STEPF(pf2, pref + 2 * NN);
      STEPF(pf3, pref + 3 * NN);
      STEPF(pf4, pref + 4 * NN);
      STEPF(pf5, pref + 5 * NN);
      STEPF(pf6, pref + 6 * NN);
      STEPF(pf7, pref + 7 * NN);
      pref += 8 * NN;
    }
  } else {
    // CL-1 steps. Fast for CL/8 - 2 iterations, clamped-index for the last 15.
    const float* pref = embr + (size_t)(t0 + 8) * NN;
    #pragma unroll 1
    for (int it = 0; it < CL / 8 - 2; ++it) {
      STEPF(pf0, pref + 0 * NN);
      STEPF(pf1, pref + 1 * NN);
      STEPF(pf2, pref + 2 * NN);
      STEPF(pf3, pref + 3 * NN);
      STEPF(pf4, pref + 4 * NN);
      STEPF(pf5, pref + 5 * NN);
      STEPF(pf6, pref + 6 * NN);
      STEPF(pf7, pref + 7 * NN);
      pref += 8 * NN;
    }
    const int tb = t0 + CL - 16;  // pf0..pf7 currently hold rows tb..tb+7
    STEPC(pf0, tb + 8);
    STEPC(pf1, tb + 9);
    STEPC(pf2, tb + 10);
    STEPC(pf3, tb + 11);
    STEPC(pf4, tb + 12);
    STEPC(pf5, tb + 13);
    STEPC(pf6, tb + 14);
    STEPC(pf7, tb + 15);
    STEPC(pf0, tb + 16);
    STEPC(pf1, tb + 17);
    STEPC(pf2, tb + 18);
    STEPC(pf3, tb + 19);
    STEPC(pf4, tb + 20);
    STEPC(pf5, tb + 21);
    STEPC(pf6, tb + 22);
  }
  #undef STEPF
  #undef STEPC
  #undef BODY

  // ---- store G[i][j] = Y[j][i], row-major bf16 [48][48]; j-pairs contiguous
  unsigned short* Gc = G + (size_t)blk * (NN * NN);
  #pragma unroll
  for (int nt = 0; nt < 3; ++nt) {
    const int rowoff = (16 * nt + rr) * NN + 4 * g;
    i32x2 d0; d0[0] = B0s[nt][0]; d0[1] = B0s[nt][1];
    i32x2 d1; d1[0] = B0s[nt][2]; d1[1] = B0s[nt][3];
    i32x2 d2; d2[0] = B1s[nt][0]; d2[1] = B1s[nt][1];
    *(i32x2*)(Gc + rowoff)      = d0;
    *(i32x2*)(Gc + rowoff + 16) = d1;
    *(i32x2*)(Gc + rowoff + 32) = d2;
  }

  // ---- gold-score partial for seq slice [c*TT/NC, (c+1)*TT/NC)
  const int* tgb = tags + (size_t)b * TT;
  const float* emb = em + (size_t)b * TT * NN;
  float sc = 0.0f;
  const int base = c * (TT / NC);
  #pragma unroll
  for (int q = 0; q < TT / NC; q += 64) {
    int tt = base + q + l;
    int tg = tgb[tt];
    sc += emb[(size_t)tt * NN + tg];
    if (tt > 0) sc += trans[tgb[tt - 1] * NN + tg];
  }
  sc = wave_reduce_sum(sc);
  if (l == 0) sc_part[blk] = sc;
}

// ---------------- Phase 2: combine chunk products + finalize ------------
template<int NC>
__launch_bounds__(64, 1)
__global__ void crf_combine_kernel(const float* __restrict__ em,
                                   const float* __restrict__ startv,
                                   const float* __restrict__ endv,
                                   const int* __restrict__ tags,
                                   const unsigned short* __restrict__ G,
                                   const float* __restrict__ sc_part,
                                   float* __restrict__ out) {
  const int b = blockIdx.x;
  const int l = threadIdx.x;
  const int jc = (l < NN) ? l : (NN - 1);
  const float* emb = em + (size_t)b * TT * NN;
  const float FSCALE = 1.0f / 48.0f;

  float r = __expf(startv[jc] + emb[jc]);

  #pragma unroll 1
  for (int c = 0; c < NC; ++c) {
    const unsigned short* Gc = G + (size_t)(b * NC + c) * (NN * NN);
    float s0 = 0.f, s1 = 0.f, s2 = 0.f, s3 = 0.f;
    #pragma unroll
    for (int i = 0; i < NN; i += 4) {
      float g0 = __uint_as_float(((unsigned)Gc[(i + 0) * NN + jc]) << 16);
      float g1 = __uint_as_float(((unsigned)Gc[(i + 1) * NN + jc]) << 16);
      float g2 = __uint_as_float(((unsigned)Gc[(i + 2) * NN + jc]) << 16);
      float g3 = __uint_as_float(((unsigned)Gc[(i + 3) * NN + jc]) << 16);
      s0 = fmaf(lane_bcast(r, i + 0), g0, s0);
      s1 = fmaf(lane_bcast(r, i + 1), g1, s1);
      s2 = fmaf(lane_bcast(r, i + 2), g2, s2);
      s3 = fmaf(lane_bcast(r, i + 3), g3, s3);
    }
    r = (s0 + s1) + (s2 + s3);
  }

  float S = wave_reduce_sum((l < NN) ? r * __expf(endv[jc]) : 0.0f);
  float scp = wave_reduce_sum((l < NC) ? sc_part[b * NC + l] : 0.0f);
  if (NC > 64) { /* not used */ }

  if (l == 0) {
    const int* tgb = tags + (size_t)b * TT;
    double K = -log((double)FSCALE);  // exact -ln(float(1/48))
    double logZ = log((double)S) + 4095.0 * K;
    double score = (double)scp + (double)startv[tgb[0]] + (double)endv[tgb[TT - 1]];
    out[b] = (float)(logZ - score);
  }
}

extern "C" void kernel_launch(void* const* d_in, const int* in_sizes, int n_in,
                              void* d_out, int out_size, void* d_ws, size_t ws_size,
                              hipStream_t stream) {
  const float* em     = (const float*)d_in[0];
  const float* trans  = (const float*)d_in[1];
  const float* startv = (const float*)d_in[2];
  const float* endv   = (const float*)d_in[3];
  const int*   tags   = (const int*)d_in[4];
  float* out = (float*)d_out;

  // ws: [G: BB*NC*48*48 bf16][sc_part: BB*NC f32]
  const size_t need64 = (size_t)BB * 64 * (NN * NN * 2 + 4);
  const size_t need32 = (size_t)BB * 32 * (NN * NN * 2 + 4);
  if (ws_size >= need64) {
    constexpr int NC = 64, CL = TT / 64;
    unsigned short* G = (unsigned short*)d_ws;
    float* sc_part = (float*)((char*)d_ws + (size_t)BB * NC * NN * NN * 2);
    hipLaunchKernelGGL((crf_chunk_kernel<NC, CL>), dim3(BB * NC), dim3(64), 0, stream,
                       em, trans, tags, G, sc_part);
    hipLaunchKernelGGL((crf_combine_kernel<NC>), dim3(BB), dim3(64), 0, stream,
                       em, startv, endv, tags, G, sc_part, out);
  } else if (ws_size >= need32) {
    constexpr int NC = 32, CL = TT / 32;
    unsigned short* G = (unsigned short*)d_ws;
    float* sc_part = (float*)((char*)d_ws + (size_t)BB * NC * NN * NN * 2);
    hipLaunchKernelGGL((crf_chunk_kernel<NC, CL>), dim3(BB * NC), dim3(64), 0, stream,
                       em, trans, tags, G, sc_part);
    hipLaunchKernelGGL((crf_combine_kernel<NC>), dim3(BB), dim3(64), 0, stream,
                       em, startv, endv, tags, G, sc_part, out);
  } else {
    constexpr int NC = 16, CL = TT / 16;
    unsigned short* G = (unsigned short*)d_ws;
    float* sc_part = (float*)((char*)d_ws + (size_t)BB * NC * NN * NN * 2);
    hipLaunchKernelGGL((crf_chunk_kernel<NC, CL>), dim3(BB * NC), dim3(64), 0, stream,
                       em, trans, tags, G, sc_part);
    hipLaunchKernelGGL((crf_combine_kernel<NC>), dim3(BB), dim3(64), 0, stream,
                       em, startv, endv, tags, G, sc_part, out);
  }
}

// Round 14
// 125.317 us; speedup vs baseline: 3.9078x; 3.9078x over previous
//
#include <hip/hip_runtime.h>
#include <cmath>

#define BB 128
#define TT 4096
#define NN 48

typedef short bf16x8 __attribute__((ext_vector_type(8)));
typedef short bf16x4 __attribute__((ext_vector_type(4)));
typedef float f32x4 __attribute__((ext_vector_type(4)));
typedef int   i32x4 __attribute__((ext_vector_type(4)));
typedef int   i32x2 __attribute__((ext_vector_type(2)));

__device__ __forceinline__ float wave_reduce_sum(float v) {
  #pragma unroll
  for (int m = 32; m >= 1; m >>= 1) v += __shfl_xor(v, m, 64);
  return v;
}
__device__ __forceinline__ float lane_bcast(float x, int lane) {
  return __uint_as_float((unsigned)__builtin_amdgcn_readlane(__float_as_int(x), lane));
}
__device__ __forceinline__ int cvt_pk_bf16(float lo, float hi) {
  int r;
  asm("v_cvt_pk_bf16_f32 %0, %1, %2" : "=v"(r) : "v"(lo), "v"(hi));
  return r;
}
__device__ __forceinline__ unsigned short f2bf(float f) {  // RNE f32->bf16
  unsigned u = __float_as_uint(f);
  unsigned r = (u + 0x7FFFu + ((u >> 16) & 1u)) >> 16;
  return (unsigned short)r;
}

// ---------------- Phase 1: per-(batch,chunk) transition-matrix product ----
// R6-verified math (absmax 0.0): Y <- diag(w_t) * E^T * Y, K-space relabel so
// C-words == next B-words verbatim.
// R14: w feeder via LDS-staged W = exp(em) as packed bf16 pairs.
//  - Once per 64 steps: stage 64 em rows (flat-linear: LDS dword p <- pack of
//    em floats 2p,2p+1 -- coalesced float2 loads, 2 exp + 1 cvt_pk per lane-
//    iter; 24 iters). ~15 cyc/step amortized.
//  - Per step: 3x ds_read_b64 at 16-lane-uniform addresses (broadcast,
//    conflict-free) + 12 unpack ops. Replaces R6's 12 ds_bpermute feeder
//    (LDS pipe ~100% subscribed) and removes per-step exp from the chain.
template<int NC, int CL>
__global__ __launch_bounds__(64) __attribute__((amdgpu_waves_per_eu(4, 4)))
void crf_chunk_kernel(const float* __restrict__ em,
                      const float* __restrict__ trans,
                      const int* __restrict__ tags,
                      unsigned short* __restrict__ G,
                      float* __restrict__ sc_part) {
  const int blk = blockIdx.x;
  const int b = blk / NC;
  const int c = blk % NC;
  const int l = threadIdx.x;
  const int g = l >> 4;
  const int rr = l & 15;
  const float FSCALE = 1.0f / 48.0f;

  // W staging buffer: 64 steps x 24 packed-bf16-pair dwords = 6 KB
  __shared__ unsigned int Wlds[64 * 24];

  // ---- static A = E^T/48. K-tile0 (16x16x32): label phi(g,e)=16*(e>>2)+4g+(e&3)
  //      K-tile1 (16x16x16): label psi(g,e)=32+4g+e
  bf16x8 Af0[3];
  bf16x4 Af1[3];
  #pragma unroll
  for (int mt = 0; mt < 3; ++mt) {
    const int i = 16 * mt + rr;
    bf16x8 a0;
    bf16x4 a1;
    #pragma unroll
    for (int e = 0; e < 8; ++e) {
      int k0 = 16 * (e >> 2) + 4 * g + (e & 3);
      a0[e] = (short)f2bf(__expf(trans[k0 * NN + i]) * FSCALE);
    }
    #pragma unroll
    for (int e = 0; e < 4; ++e) {
      int k1 = 32 + 4 * g + e;
      a1[e] = (short)f2bf(__expf(trans[k1 * NN + i]) * FSCALE);
    }
    Af0[mt] = a0; Af1[mt] = a1;
  }

  // ---- persistent state: Y = I in B-quad encoding.
  i32x4 B0s[3];
  i32x2 B1s[3];
  #pragma unroll
  for (int nt = 0; nt < 3; ++nt) {
    const int col = 16 * nt + rr;
    i32x4 b0;
    i32x2 b1;
    #pragma unroll
    for (int w = 0; w < 4; ++w) {
      int r0 = 16 * (w >> 1) + 4 * g + 2 * (w & 1);
      b0[w] = ((r0 == col) ? 0x3F80 : 0) | (((r0 + 1 == col) ? 0x3F80 : 0) << 16);
    }
    #pragma unroll
    for (int w = 0; w < 2; ++w) {
      int r0 = 32 + 4 * g + 2 * w;
      b1[w] = ((r0 == col) ? 0x3F80 : 0) | (((r0 + 1 == col) ? 0x3F80 : 0) << 16);
    }
    B0s[nt] = b0; B1s[nt] = b1;
  }

  const f32x4 zq = {0.f, 0.f, 0.f, 0.f};

  const int t0 = c * CL + 1;
  const float* emb = em + (size_t)b * TT * NN;

  #define U2F(x) __uint_as_float(x)

  // one step, reading step S (local index into Wlds)
  #define STEP(S) do {                                                        \
    const unsigned int* wrow_ = &Wlds[(S) * 24 + 2 * g];                      \
    unsigned int q0x_ = wrow_[0],  q0y_ = wrow_[1];                           \
    unsigned int q1x_ = wrow_[8],  q1y_ = wrow_[9];                           \
    unsigned int q2x_ = wrow_[16], q2y_ = wrow_[17];                          \
    float wb_[12];                                                            \
    wb_[0]  = U2F(q0x_ << 16); wb_[1]  = U2F(q0x_ & 0xFFFF0000u);             \
    wb_[2]  = U2F(q0y_ << 16); wb_[3]  = U2F(q0y_ & 0xFFFF0000u);             \
    wb_[4]  = U2F(q1x_ << 16); wb_[5]  = U2F(q1x_ & 0xFFFF0000u);             \
    wb_[6]  = U2F(q1y_ << 16); wb_[7]  = U2F(q1y_ & 0xFFFF0000u);             \
    wb_[8]  = U2F(q2x_ << 16); wb_[9]  = U2F(q2x_ & 0xFFFF0000u);             \
    wb_[10] = U2F(q2y_ << 16); wb_[11] = U2F(q2y_ & 0xFFFF0000u);             \
    _Pragma("unroll") for (int nt = 0; nt < 3; ++nt) {                        \
      bf16x4 b1c_ = __builtin_bit_cast(bf16x4, B1s[nt]);                      \
      bf16x8 b0c_ = __builtin_bit_cast(bf16x8, B0s[nt]);                      \
      f32x4 a0_ = __builtin_amdgcn_mfma_f32_16x16x16bf16_1k(Af1[0], b1c_, zq, 0, 0, 0); \
      f32x4 a1_ = __builtin_amdgcn_mfma_f32_16x16x16bf16_1k(Af1[1], b1c_, zq, 0, 0, 0); \
      f32x4 a2_ = __builtin_amdgcn_mfma_f32_16x16x16bf16_1k(Af1[2], b1c_, zq, 0, 0, 0); \
      a0_ = __builtin_amdgcn_mfma_f32_16x16x32_bf16(Af0[0], b0c_, a0_, 0, 0, 0); \
      a1_ = __builtin_amdgcn_mfma_f32_16x16x32_bf16(Af0[1], b0c_, a1_, 0, 0, 0); \
      a2_ = __builtin_amdgcn_mfma_f32_16x16x32_bf16(Af0[2], b0c_, a2_, 0, 0, 0); \
      B0s[nt][0] = cvt_pk_bf16(a0_[0] * wb_[0],  a0_[1] * wb_[1]);            \
      B0s[nt][1] = cvt_pk_bf16(a0_[2] * wb_[2],  a0_[3] * wb_[3]);            \
      B0s[nt][2] = cvt_pk_bf16(a1_[0] * wb_[4],  a1_[1] * wb_[5]);            \
      B0s[nt][3] = cvt_pk_bf16(a1_[2] * wb_[6],  a1_[3] * wb_[7]);            \
      B1s[nt][0] = cvt_pk_bf16(a2_[0] * wb_[8],  a2_[1] * wb_[9]);            \
      B1s[nt][1] = cvt_pk_bf16(a2_[2] * wb_[10], a2_[3] * wb_[11]);           \
    }                                                                         \
  } while (0)

  // two halves of the chunk: stage 64 rows of W = exp(em), then 64 steps.
  #pragma unroll 1
  for (int h = 0; h < 2; ++h) {
    const int rowbase = t0 + 64 * h;
    // last chunk, second half: only 63 rows (t = ..., TT-1)
    const int nrows = (c == NC - 1 && h == 1) ? 63 : 64;

    __syncthreads();  // all reads of previous half's W done (single wave: waitcnt)
    {
      const float* src = emb + (size_t)rowbase * NN;
      const int maxfi = nrows * NN - 2;  // clamp for the 63-row tail
      #pragma unroll 4
      for (int it = 0; it < 24; ++it) {
        int p = it * 64 + l;
        int fi = 2 * p;
        fi = (fi > maxfi) ? maxfi : fi;
        float2 v = *(const float2*)(src + fi);
        Wlds[p] = (unsigned)cvt_pk_bf16(__expf(v.x), __expf(v.y));
      }
    }
    __syncthreads();  // W visible before consumption

    #pragma unroll 1
    for (int s = 0; s < nrows; s += 4) {
      STEP(s + 0);
      STEP(s + 1);
      STEP(s + 2);
      if (s + 3 < nrows) STEP(s + 3);   // nrows=63 tail: skip the 64th
    }
  }
  #undef STEP
  #undef U2F

  // ---- store G[i][j] = Y[j][i], row-major bf16 [48][48]; j-pairs contiguous
  unsigned short* Gc = G + (size_t)blk * (NN * NN);
  #pragma unroll
  for (int nt = 0; nt < 3; ++nt) {
    const int rowoff = (16 * nt + rr) * NN + 4 * g;
    i32x2 d0; d0[0] = B0s[nt][0]; d0[1] = B0s[nt][1];
    i32x2 d1; d1[0] = B0s[nt][2]; d1[1] = B0s[nt][3];
    i32x2 d2; d2[0] = B1s[nt][0]; d2[1] = B1s[nt][1];
    *(i32x2*)(Gc + rowoff)      = d0;
    *(i32x2*)(Gc + rowoff + 16) = d1;
    *(i32x2*)(Gc + rowoff + 32) = d2;
  }

  // ---- gold-score partial for seq slice [c*TT/NC, (c+1)*TT/NC)
  const int* tgb = tags + (size_t)b * TT;
  float sc = 0.0f;
  const int base = c * (TT / NC);
  #pragma unroll
  for (int q = 0; q < TT / NC; q += 64) {
    int tt = base + q + l;
    int tg = tgb[tt];
    sc += emb[(size_t)tt * NN + tg];
    if (tt > 0) sc += trans[tgb[tt - 1] * NN + tg];
  }
  sc = wave_reduce_sum(sc);
  if (l == 0) sc_part[blk] = sc;
}

// ---------------- Phase 2: combine chunk products + finalize ------------
template<int NC>
__launch_bounds__(64, 1)
__global__ void crf_combine_kernel(const float* __restrict__ em,
                                   const float* __restrict__ startv,
                                   const float* __restrict__ endv,
                                   const int* __restrict__ tags,
                                   const unsigned short* __restrict__ G,
                                   const float* __restrict__ sc_part,
                                   float* __restrict__ out) {
  const int b = blockIdx.x;
  const int l = threadIdx.x;
  const int jc = (l < NN) ? l : (NN - 1);
  const float* emb = em + (size_t)b * TT * NN;
  const float FSCALE = 1.0f / 48.0f;

  float r = __expf(startv[jc] + emb[jc]);

  #pragma unroll 1
  for (int c = 0; c < NC; ++c) {
    const unsigned short* Gc = G + (size_t)(b * NC + c) * (NN * NN);
    float s0 = 0.f, s1 = 0.f, s2 = 0.f, s3 = 0.f;
    #pragma unroll
    for (int i = 0; i < NN; i += 4) {
      float g0 = __uint_as_float(((unsigned)Gc[(i + 0) * NN + jc]) << 16);
      float g1 = __uint_as_float(((unsigned)Gc[(i + 1) * NN + jc]) << 16);
      float g2 = __uint_as_float(((unsigned)Gc[(i + 2) * NN + jc]) << 16);
      float g3 = __uint_as_float(((unsigned)Gc[(i + 3) * NN + jc]) << 16);
      s0 = fmaf(lane_bcast(r, i + 0), g0, s0);
      s1 = fmaf(lane_bcast(r, i + 1), g1, s1);
      s2 = fmaf(lane_bcast(r, i + 2), g2, s2);
      s3 = fmaf(lane_bcast(r, i + 3), g3, s3);
    }
    r = (s0 + s1) + (s2 + s3);
  }

  float S = wave_reduce_sum((l < NN) ? r * __expf(endv[jc]) : 0.0f);
  float scp = wave_reduce_sum((l < NC) ? sc_part[b * NC + l] : 0.0f);

  if (l == 0) {
    const int* tgb = tags + (size_t)b * TT;
    double K = -log((double)FSCALE);  // exact -ln(float(1/48))
    double logZ = log((double)S) + 4095.0 * K;
    double score = (double)scp + (double)startv[tgb[0]] + (double)endv[tgb[TT - 1]];
    out[b] = (float)(logZ - score);
  }
}

extern "C" void kernel_launch(void* const* d_in, const int* in_sizes, int n_in,
                              void* d_out, int out_size, void* d_ws, size_t ws_size,
                              hipStream_t stream) {
  const float* em     = (const float*)d_in[0];
  const float* trans  = (const float*)d_in[1];
  const float* startv = (const float*)d_in[2];
  const float* endv   = (const float*)d_in[3];
  const int*   tags   = (const int*)d_in[4];
  float* out = (float*)d_out;

  // ws: [G: BB*NC*48*48 bf16][sc_part: BB*NC f32]
  const size_t need32 = (size_t)BB * 32 * (NN * NN * 2 + 4);
  if (ws_size >= need32) {
    constexpr int NC = 32, CL = TT / 32;
    unsigned short* G = (unsigned short*)d_ws;
    float* sc_part = (float*)((char*)d_ws + (size_t)BB * NC * NN * NN * 2);
    hipLaunchKernelGGL((crf_chunk_kernel<NC, CL>), dim3(BB * NC), dim3(64), 0, stream,
                       em, trans, tags, G, sc_part);
    hipLaunchKernelGGL((crf_combine_kernel<NC>), dim3(BB), dim3(64), 0, stream,
                       em, startv, endv, tags, G, sc_part, out);
  } else {
    constexpr int NC = 16, CL = TT / 16;
    unsigned short* G = (unsigned short*)d_ws;
    float* sc_part = (float*)((char*)d_ws + (size_t)BB * NC * NN * NN * 2);
    hipLaunchKernelGGL((crf_chunk_kernel<NC, CL>), dim3(BB * NC), dim3(64), 0, stream,
                       em, trans, tags, G, sc_part);
    hipLaunchKernelGGL((crf_combine_kernel<NC>), dim3(BB), dim3(64), 0, stream,
                       em, startv, endv, tags, G, sc_part, out);
  }
}